// Round 7
// baseline (116.836 us; speedup 1.0000x reference)
//
#include <hip/hip_runtime.h>

#define HCH 32
#define NDIM 1024
#define SEG 512                  // pixels per half-row unit
#define PAIRS (SEG / 64)         // 8 iterations of 64 px (2 MFMA tiles)
#define HRPW 4                   // half-row units per wave
#define NBLOCKS 512              // 8192 units / (4 waves * HRPW)

using half2v   = __attribute__((ext_vector_type(2))) _Float16;
using half8    = __attribute__((ext_vector_type(8))) _Float16;
using floatx16 = __attribute__((ext_vector_type(16))) float;

// DIAGNOSTIC-STRUCTURE ROUND: same inner math as R6 (dual 32x32 MFMA tiles,
// single-shuffle epilogue, LDS-staged streams), but grid/4 with 4 sequential
// half-row units per wave (double-buffered LDS, depth-1 unit prefetch, no
// barriers). Purpose: halve resident parallelism at constant per-CU work so
// the kernel either (a) stays ~34us -> throughput-bound, or (b) grows to
// ~70us and becomes visible in rocprof top-5 -> latency-bound + counters.
__global__ __launch_bounds__(256, 4)
void lf_kernel(const float* __restrict__ weights,
               const float* __restrict__ distances,
               const float* __restrict__ W1,
               const float* __restrict__ b1,
               const float* __restrict__ W2,
               const float* __restrict__ b2,
               const float* __restrict__ W3,
               const float* __restrict__ b3,
               float* __restrict__ out)
{
    __shared__ float sd[4][2][SEG];   // per-wave private, double-buffered
    __shared__ float sw[4][2][SEG];

    const int lane = threadIdx.x & 63;
    const int wv = threadIdx.x >> 6;
    const int wave_gid = blockIdx.x * 4 + wv;       // 0..2047
    const int unit0 = wave_gid * HRPW;              // first half-row unit

    const int col = lane & 31;                      // pixel-in-tile
    const int half_id = lane >> 5;
    const bool hi = (half_id != 0);
    const int kb = half_id * 8;                     // k-block base for frags

    // ---- Issue unit0's stream loads FIRST (4 KB/wave in flight) ----
    const int r0 = unit0 >> 1;
    const int jb0 = (unit0 & 1) * SEG;
    const float* __restrict__ dr0 = distances + (size_t)r0 * NDIM + jb0;
    const float* __restrict__ wr0 = weights + (r0 >> 10) * NDIM + jb0;
    const float4 d0 = *(const float4*)(dr0 + 4 * lane);
    const float4 d1 = *(const float4*)(dr0 + 256 + 4 * lane);
    const float4 w0 = *(const float4*)(wr0 + 4 * lane);
    const float4 w1v = *(const float4*)(wr0 + 256 + 4 * lane);

    // ---- Weight prologue (overlaps the stream loads) ----
    // Layer-1 j/d coefficients and W1[0]/b1 rows as f16 pairs.
    half2v cc2[8], ee2[8], w10h[8], b10h[8];
#pragma unroll
    for (int p = 0; p < 8; ++p) {
        const int chA = (p < 4) ? (kb + 2 * p) : (16 + kb + 2 * (p - 4));
        const int chB = chA + 1;
        cc2[p]  = half2v{(_Float16)W1[HCH + chA],     (_Float16)W1[HCH + chB]};
        ee2[p]  = half2v{(_Float16)W1[2 * HCH + chA], (_Float16)W1[2 * HCH + chB]};
        w10h[p] = half2v{(_Float16)W1[chA],           (_Float16)W1[chB]};
        b10h[p] = half2v{(_Float16)b1[chA],           (_Float16)b1[chB]};
    }

    // A fragments: A[m=c][k=h] = W2[h][c]; c = col, h = kb+j / 16+kb+j.
    half8 a0, a1;
#pragma unroll
    for (int j = 0; j < 8; ++j) {
        a0[j] = (_Float16)W2[(kb + j) * HCH + col];
        a1[j] = (_Float16)W2[(16 + kb + j) * HCH + col];
    }

    // C-init = b2; W3 per accumulator register.
    // D row for reg r: (r&3) + 8*(r>>2) + 4*half_id  [measured 32x32 layout]
    floatx16 cinit;
    float w3r[16];
#pragma unroll
    for (int r = 0; r < 16; ++r) {
        const int rc = (r & 3) + 8 * (r >> 2) + 4 * half_id;
        cinit[r] = b2[rc];
        w3r[r]   = W3[rc];
    }
    const float b3v = b3[0];

    // ---- Park unit0's streams into LDS buffer 0 ----
    *(float4*)&sd[wv][0][4 * lane]       = d0;
    *(float4*)&sd[wv][0][256 + 4 * lane] = d1;
    *(float4*)&sw[wv][0][4 * lane]       = w0;
    *(float4*)&sw[wv][0][256 + 4 * lane] = w1v;

    const half2v zero2 = half2v{(_Float16)0.0f, (_Float16)0.0f};

    for (int t = 0; t < HRPW; ++t) {
        const int unit = unit0 + t;
        const int row_id = unit >> 1;
        const int jb = (unit & 1) * SEG;
        const int buf = t & 1;

        // ---- Prefetch next unit's streams (covers HBM latency under compute) ----
        const int un = (t + 1 < HRPW) ? (unit + 1) : unit0;
        const int rn = un >> 1;
        const int jbn = (un & 1) * SEG;
        const float* __restrict__ drn = distances + (size_t)rn * NDIM + jbn;
        const float* __restrict__ wrn = weights + (rn >> 10) * NDIM + jbn;
        const float4 pd0 = *(const float4*)(drn + 4 * lane);
        const float4 pd1 = *(const float4*)(drn + 256 + 4 * lane);
        const float4 pw0 = *(const float4*)(wrn + 4 * lane);
        const float4 pw1 = *(const float4*)(wrn + 256 + 4 * lane);

        // ---- Per-row layer-1 base: base = W1[0]*wi + b1 (packed f16) ----
        const float wi = weights[row_id];
        const _Float16 wih = (_Float16)wi;
        const half2v wi2 = half2v{wih, wih};
        half2v base2[8];
#pragma unroll
        for (int p = 0; p < 8; ++p)
            base2[p] = __builtin_elementwise_fma(w10h[p], wi2, b10h[p]);

        float* __restrict__ orow = out + (size_t)row_id * NDIM + jb;

#pragma unroll
        for (int p = 0; p < PAIRS; ++p) {
            const float dA = sd[wv][buf][p * 64 + col];
            const float dB = sd[wv][buf][p * 64 + 32 + col];
            const float wA = sw[wv][buf][p * 64 + col];
            const float wB = sw[wv][buf][p * 64 + 32 + col];

            // ---- Layer 1 (packed f16), two independent tiles ----
            const _Float16 dhA = (_Float16)dA, wjhA = (_Float16)wA;
            const _Float16 dhB = (_Float16)dB, wjhB = (_Float16)wB;
            const half2v d2A = half2v{dhA, dhA}, wj2A = half2v{wjhA, wjhA};
            const half2v d2B = half2v{dhB, dhB}, wj2B = half2v{wjhB, wjhB};

            union Frag { half8 v; half2v h[4]; } f0A, f1A, f0B, f1B;
#pragma unroll
            for (int q = 0; q < 4; ++q) {
                half2v tA0 = __builtin_elementwise_fma(cc2[q], wj2A, base2[q]);
                tA0 = __builtin_elementwise_fma(ee2[q], d2A, tA0);
                f0A.h[q] = __builtin_elementwise_max(tA0, zero2);
                half2v tA1 = __builtin_elementwise_fma(cc2[q + 4], wj2A, base2[q + 4]);
                tA1 = __builtin_elementwise_fma(ee2[q + 4], d2A, tA1);
                f1A.h[q] = __builtin_elementwise_max(tA1, zero2);
                half2v tB0 = __builtin_elementwise_fma(cc2[q], wj2B, base2[q]);
                tB0 = __builtin_elementwise_fma(ee2[q], d2B, tB0);
                f0B.h[q] = __builtin_elementwise_max(tB0, zero2);
                half2v tB1 = __builtin_elementwise_fma(cc2[q + 4], wj2B, base2[q + 4]);
                tB1 = __builtin_elementwise_fma(ee2[q + 4], d2B, tB1);
                f1B.h[q] = __builtin_elementwise_max(tB1, zero2);
            }

            // ---- Layer 2: two independent MFMA chains ----
            floatx16 accA = __builtin_amdgcn_mfma_f32_32x32x16_f16(a0, f0A.v, cinit, 0, 0, 0);
            floatx16 accB = __builtin_amdgcn_mfma_f32_32x32x16_f16(a0, f0B.v, cinit, 0, 0, 0);
            accA = __builtin_amdgcn_mfma_f32_32x32x16_f16(a1, f1A.v, accA, 0, 0, 0);
            accB = __builtin_amdgcn_mfma_f32_32x32x16_f16(a1, f1B.v, accB, 0, 0, 0);

            // ---- Layer 3: relu + W3 dot, two tiles interleaved ----
            float sA0 = 0.0f, sA1 = 0.0f, sB0 = 0.0f, sB1 = 0.0f;
#pragma unroll
            for (int r = 0; r < 16; r += 2) {
                sA0 = fmaf(fmaxf(accA[r + 0], 0.0f), w3r[r + 0], sA0);
                sA1 = fmaf(fmaxf(accA[r + 1], 0.0f), w3r[r + 1], sA1);
                sB0 = fmaf(fmaxf(accB[r + 0], 0.0f), w3r[r + 0], sB0);
                sB1 = fmaf(fmaxf(accB[r + 1], 0.0f), w3r[r + 1], sB1);
            }
            const float sA = sA0 + sA1;
            const float sB = sB0 + sB1;

            // One shuffle resolves both tiles.
            const float u = hi ? sA : sB;
            const float other = __shfl_xor(u, 32, 64);
            const float loc = hi ? sB : sA;
            const float full = loc + other;

            // softplus(x) = max(x,0) + log(1 + exp(-|x|))
            const float x = full + b3v;
            const float sp = fmaxf(x, 0.0f) + __logf(1.0f + __expf(-fabsf(x)));

            orow[p * 64 + lane] = sp;    // coalesced 256B, all 64 lanes
        }

        // ---- Park prefetched streams for the next unit ----
        *(float4*)&sd[wv][buf ^ 1][4 * lane]       = pd0;
        *(float4*)&sd[wv][buf ^ 1][256 + 4 * lane] = pd1;
        *(float4*)&sw[wv][buf ^ 1][4 * lane]       = pw0;
        *(float4*)&sw[wv][buf ^ 1][256 + 4 * lane] = pw1;
    }
}

extern "C" void kernel_launch(void* const* d_in, const int* in_sizes, int n_in,
                              void* d_out, int out_size, void* d_ws, size_t ws_size,
                              hipStream_t stream) {
    const float* weights   = (const float*)d_in[0];
    const float* distances = (const float*)d_in[1];
    const float* W1 = (const float*)d_in[2];
    const float* b1 = (const float*)d_in[3];
    const float* W2 = (const float*)d_in[4];
    const float* b2 = (const float*)d_in[5];
    const float* W3 = (const float*)d_in[6];
    const float* b3 = (const float*)d_in[7];
    float* out = (float*)d_out;

    lf_kernel<<<dim3(NBLOCKS), 256, 0, stream>>>(weights, distances,
                                                 W1, b1, W2, b2, W3, b3, out);
}